// Round 8
// baseline (407.073 us; speedup 1.0000x reference)
//
#include <hip/hip_runtime.h>
#include <hip/hip_bf16.h>
#include <stdint.h>

// Problem constants: B=4, S=2048, D=1024, H=16, Dh=64
#define LOG2E 1.44269504088896340736f
#define SCL   (0.125f * LOG2E)   // folded into Q at the gemm epilogue

typedef __attribute__((ext_vector_type(8)))  short short8;     // 8 bf16 (4 VGPRs)
typedef __attribute__((ext_vector_type(16))) float floatx16;   // 32x32 C/D frag
typedef __attribute__((ext_vector_type(4)))  unsigned short ushort4v;

// global -> LDS direct DMA, 16B/lane. LDS dest is HW-fixed: wave-uniform base + lane*16.
#define GLP(g, l)                                                              \
    __builtin_amdgcn_global_load_lds(                                          \
        (const __attribute__((address_space(1))) void*)(g),                    \
        (__attribute__((address_space(3))) void*)(l), 16, 0, 0)

#if __has_builtin(__builtin_amdgcn_exp2f)
#define EXP2(x) __builtin_amdgcn_exp2f(x)   // raw v_exp_f32 (args bounded here)
#else
#define EXP2(x) exp2f(x)
#endif

static __device__ __forceinline__ unsigned short f2bf(float f) {
    union { float f; unsigned u; } v; v.f = f;
    unsigned r = v.u + 0x7FFFu + ((v.u >> 16) & 1u);  // RNE
    return (unsigned short)(r >> 16);
}

static __device__ __forceinline__ unsigned pack2bf(float a, float b) {
    __hip_bfloat162 h = __float22bfloat162_rn(make_float2(a, b));
    union { __hip_bfloat162 h; unsigned u; } c; c.h = h; return c.u;
}

// exp2 8 consecutive S-regs -> one bf16x8 PV A-frag + running l accumulation
#define EXPPACKL(dst, sv, base, lacc) do {                                     \
        float p0 = EXP2((sv)[(base) + 0]), p1 = EXP2((sv)[(base) + 1]);        \
        float p2 = EXP2((sv)[(base) + 2]), p3 = EXP2((sv)[(base) + 3]);        \
        float p4 = EXP2((sv)[(base) + 4]), p5 = EXP2((sv)[(base) + 5]);        \
        float p6 = EXP2((sv)[(base) + 6]), p7 = EXP2((sv)[(base) + 7]);        \
        lacc += ((p0 + p1) + (p2 + p3)) + ((p4 + p5) + (p6 + p7));             \
        dst.uu[0] = pack2bf(p0, p1); dst.uu[1] = pack2bf(p2, p3);              \
        dst.uu[2] = pack2bf(p4, p5); dst.uu[3] = pack2bf(p6, p7);              \
    } while (0)

// ------- merged fp32->bf16 convert: X | Wq|Wk|Wv | mask(xLOG2E) in one launch -------
__global__ __launch_bounds__(256) void cvt_all(const float* __restrict__ X,
                                               const float* __restrict__ Wq,
                                               const float* __restrict__ Wk,
                                               const float* __restrict__ Wv,
                                               const float* __restrict__ mask,
                                               unsigned short* __restrict__ xb,
                                               unsigned short* __restrict__ wb,
                                               float* __restrict__ maskl) {
    int i = blockIdx.x * 256 + threadIdx.x;   // 2097152 X + 786432 W + 2048 mask float4s
    if (i < 2097152) {
        float4 v = ((const float4*)X)[i];
        ushort4v o;
        o.x = f2bf(v.x); o.y = f2bf(v.y); o.z = f2bf(v.z); o.w = f2bf(v.w);
        ((ushort4v*)xb)[i] = o;
    } else if (i < 2883584) {
        int j = i - 2097152;
        const float* src; int k;
        if (j < 262144)      { src = Wq; k = j; }
        else if (j < 524288) { src = Wk; k = j - 262144; }
        else                 { src = Wv; k = j - 524288; }
        float4 v = ((const float4*)src)[k];
        ushort4v o;
        o.x = f2bf(v.x); o.y = f2bf(v.y); o.z = f2bf(v.z); o.w = f2bf(v.w);
        ((ushort4v*)wb)[j] = o;
    } else if (i < 2883584 + 2048) {
        int j = i - 2883584;
        float4 v = ((const float4*)mask)[j];
        ((float4*)maskl)[j] = make_float4(v.x * LOG2E, v.y * LOG2E,
                                          v.z * LOG2E, v.w * LOG2E);
    }
}

// ---------------- fused QKV projection GEMM (32x32x16 MFMA) ----------------
// (R7 structure, kept: 256x256 block, 8 waves as 2Mx4N -> 128x64 wave-tiles,
// dbuf 128KB LDS, prefetch-first + one vmcnt(0)+barrier per BK=64 tile.)
__global__ __launch_bounds__(512)
__attribute__((amdgpu_waves_per_eu(2, 2))) void qkv_gemm(
        const unsigned short* __restrict__ X,   // [8192][1024] bf16
        const unsigned short* __restrict__ W,   // [3072][1024] bf16
        const float* __restrict__ bq, const float* __restrict__ bk,
        const float* __restrict__ bv,
        unsigned short* __restrict__ Qf,        // [8192][1024]  (pre-scaled by SCL)
        unsigned short* __restrict__ Kf,        // [8192][1024]
        unsigned short* __restrict__ Vt)        // [64*64][2048], key-permuted
{
    // A slot0 @0, A slot1 @16384, B slot0 @32768, B slot1 @49152 (ushorts)
    __shared__ __align__(16) unsigned short AB[65536];          // 128 KB

    const int tid  = threadIdx.x;
    const int lane = tid & 63;
    const int wv   = tid >> 6;            // 0..7
    const int q32  = lane & 31;
    const int hi   = lane >> 5;
    const int sw   = q32 & 7;
    const int mBase = blockIdx.x * 256;
    const int nBase = blockIdx.y * 256;
    const int wm = (wv >> 2) * 128;       // 0 or 128
    const int wn = (wv & 3) * 64;         // 0,64,128,192

    floatx16 acc[4][2];
#pragma unroll
    for (int mi = 0; mi < 4; ++mi) { acc[mi][0] = 0.0f; acc[mi][1] = 0.0f; }

    const int sr = lane >> 3;             // 0..7 row-in-group
    const int kc = (lane & 7) ^ sr;       // swizzled 16B chunk

    // hoisted LDS read bases (R&7 == sw since wm, mi*32, wn, ni*32 are mult of 8)
    const unsigned short* aBase[4];
    const unsigned short* bBase[4];
#pragma unroll
    for (int ks = 0; ks < 4; ++ks) {
        const int cs = ((2 * ks + hi) ^ sw) * 8;
        aBase[ks] = AB + ((wv >> 2) * 16 + (q32 >> 3)) * 512 + sw * 64 + cs;
        bBase[ks] = AB + 32768 + ((wv & 3) * 8 + (q32 >> 3)) * 512 + sw * 64 + cs;
    }

    // stage K-tile (kb) into slot (ushort offset so): 4 rounds x (1 A + 1 B) GLP
    auto STAGE = [&](int kb, int so) {
#pragma unroll
        for (int r = 0; r < 4; ++r) {
            const int seg = r * 8 + wv;                      // 0..31
            const int row = seg * 8 + sr;                    // 0..255
            GLP(X + (size_t)(mBase + row) * 1024 + kb + kc * 8, AB + so + seg * 512);
            GLP(W + (size_t)(nBase + row) * 1024 + kb + kc * 8, AB + 32768 + so + seg * 512);
        }
    };

    // prologue: stage tile 0 -> slot 0
    STAGE(0, 0);
    asm volatile("s_waitcnt vmcnt(0)" ::: "memory");
    __builtin_amdgcn_s_barrier();

#pragma unroll 1
    for (int t = 0; t < 16; ++t) {
        const int so  = (t & 1) * 16384;
        // prefetch tile t+1 into the slot freed at the end of tile t-1
        if (t < 15) STAGE((t + 1) * 64, ((t + 1) & 1) * 16384);
        // compute tile t
        short8 bF[2][4];
#pragma unroll
        for (int ni = 0; ni < 2; ++ni)
#pragma unroll
            for (int ks = 0; ks < 4; ++ks)
                bF[ni][ks] = *(const short8*)(bBase[ks] + so + ni * 2048);
#pragma unroll
        for (int mi = 0; mi < 4; ++mi) {
            short8 aF[4];
#pragma unroll
            for (int ks = 0; ks < 4; ++ks)
                aF[ks] = *(const short8*)(aBase[ks] + so + mi * 2048);
#pragma unroll
            for (int ks = 0; ks < 4; ++ks) {
                acc[mi][0] = __builtin_amdgcn_mfma_f32_32x32x16_bf16(
                    aF[ks], bF[0][ks], acc[mi][0], 0, 0, 0);
                acc[mi][1] = __builtin_amdgcn_mfma_f32_32x32x16_bf16(
                    aF[ks], bF[1][ks], acc[mi][1], 0, 0, 0);
            }
        }
        // own ds_reads drained (lgkm) + prefetch landed (vm); barrier frees slot so
        asm volatile("s_waitcnt vmcnt(0) lgkmcnt(0)" ::: "memory");
        __builtin_amdgcn_s_barrier();
    }

    // 32x32 C/D layout: col = lane&31, row = (r&3) + 8*(r>>2) + 4*hi (+ mi*32)
    if (blockIdx.y < 8) {
        // ---- Q or K: LDS transpose (two 128-row halves) -> coalesced stores ----
        unsigned short* dst = (blockIdx.y < 4) ? Qf : Kf;
        const float* bias   = (blockIdx.y < 4) ? bq : bk;
        const float scl     = (blockIdx.y < 4) ? SCL : 1.0f;
        const int nb = nBase & 1023;
        float bj[2];
#pragma unroll
        for (int ni = 0; ni < 2; ++ni)
            bj[ni] = bias[nb + wn + ni * 32 + q32];
#pragma unroll 1
        for (int hh = 0; hh < 2; ++hh) {
            if ((wm >> 7) == hh) {   // the 4 waves owning this M-half stage it
#pragma unroll
                for (int ni = 0; ni < 2; ++ni) {
                    const int col = wn + ni * 32 + q32;
#pragma unroll
                    for (int mi = 0; mi < 4; ++mi)
#pragma unroll
                        for (int g = 0; g < 4; ++g) {
                            const int row0 = mi * 32 + g * 8 + hi * 4;
#pragma unroll
                            for (int rr = 0; rr < 4; ++rr)
                                AB[(row0 + rr) * 264 + col] =
                                    f2bf((acc[mi][ni][g * 4 + rr] + bj[ni]) * scl);
                        }
                }
            }
            __syncthreads();
            // 128 rows x 32 parts; 512 threads -> 16 rows/iter, 8 iters
#pragma unroll
            for (int it = 0; it < 8; ++it) {
                const int row  = it * 16 + (tid >> 5);
                const int part = tid & 31;
                short8 v = *(const short8*)(AB + row * 264 + part * 8);
                *(short8*)(dst + (size_t)(mBase + hh * 128 + row) * 1024
                               + nb + part * 8) = v;
            }
            __syncthreads();   // before the other half overwrites AB
        }
    } else {
        // ---- V: transposed stores with key bits 2<->3 swapped (quad-aligned) ----
#pragma unroll
        for (int ni = 0; ni < 2; ++ni) {
            const int c = (nBase - 2048) + wn + ni * 32 + q32;   // 0..1023
            const int h = c >> 6;
            const int d = c & 63;
            const float bias = bv[c];
#pragma unroll
            for (int mi = 0; mi < 4; ++mi)
#pragma unroll
                for (int g = 0; g < 4; ++g) {
                    const int m0 = mBase + wm + mi * 32 + g * 8 + hi * 4;
                    const int b  = m0 >> 11;
                    const int s0 = m0 & 2047;
                    const int sp = (s0 & ~12) | ((s0 & 4) << 1) | ((s0 & 8) >> 1);
                    ushort4v pv;
#pragma unroll
                    for (int rr = 0; rr < 4; ++rr)
                        pv[rr] = f2bf(acc[mi][ni][g * 4 + rr] + bias);
                    *(ushort4v*)(Vt + (size_t)((b * 16 + h) * 64 + d) * 2048 + sp) = pv;
                }
        }
    }
}

// ---------------- flash attention: 32x32 MFMA, S^T, zero-exchange P ----------------
// R8: the R6 counters showed the three pipes SERIALIZED (MFMA 34 + LDS ~25 +
// VALU ~25 ~= 92us measured): 2 barrier-locked waves/SIMD have no TLP, and the
// unroll-1 subtile loop forbade in-wave interleave. Fix: 2-deep SUBTILE SOFTWARE
// PIPELINE -- while subtile t's exp/pack (VALU) + PV (MFMA) retire, subtile t+1's
// K/mask ds_reads + S-MFMAs sit in the same scheduling region (independent
// chains -> scheduler weaves; exp issues during 8-cyc MFMA occupancy).
// sched_barrier(0) at phase boundaries caps liveness (anti-R3-spill) while
// leaving intra-phase freedom. The lacc ones-trick is DROPPED (frees 32 regs for
// the 2nd s-state, cuts MFMA work 25%); l back on VALU + Lsh epilogue (R4-style).
__global__ __launch_bounds__(256)
__attribute__((amdgpu_waves_per_eu(2, 2))) void attn_kernel(
        const unsigned short* __restrict__ Qf,   // [8192][1024] bf16 (x SCL)
        const unsigned short* __restrict__ Kf,   // [8192][1024] bf16
        const unsigned short* __restrict__ VT,   // [64*64][2048] bf16, key-permuted
        const float* __restrict__ maskl,         // [4][2048], pre-scaled by LOG2E
        float* __restrict__ out)                 // [4][2048][1024]
{
    __shared__ __align__(16) unsigned short Ksh[2 * 128 * 64]; // 2 x (128 keys x 64 d)
    __shared__ __align__(16) unsigned short Vsh[2 * 64 * 128]; // 2 x (64 d x 128 keys)
    __shared__ __align__(16) float Mall[2048];                 // whole mask row, once
    __shared__ __align__(16) float Lsh[256];                   // 1/l(q), end only

    const int tid  = threadIdx.x;
    const int lane = tid & 63;
    const int wv   = tid >> 6;
    const int q32  = lane & 31;
    const int hi   = lane >> 5;
    const int bh   = blockIdx.x & 63;
    const int qt   = blockIdx.x >> 6;                // 0..7
    const int b    = bh >> 4;
    const int h    = bh & 15;
    const int q0   = qt * 256 + wv * 64;             // wave owns 64 queries
    const int sw   = q32 & 7;                        // per-lane XOR swizzle key

    // Q as B-operand fragments for both q-subtiles, hoisted out of K-loop
    short8 bQ0[4], bQ1[4];
#pragma unroll
    for (int ks = 0; ks < 4; ++ks) {
        bQ0[ks] = *(const short8*)(Qf + (size_t)(b * 2048 + q0 + q32) * 1024
                                      + h * 64 + ks * 16 + hi * 8);
        bQ1[ks] = *(const short8*)(Qf + (size_t)(b * 2048 + q0 + 32 + q32) * 1024
                                      + h * 64 + ks * 16 + hi * 8);
    }

    floatx16 accO00 = 0.0f, accO01 = 0.0f;   // qsub0: d-lo, d-hi
    floatx16 accO10 = 0.0f, accO11 = 0.0f;   // qsub1
    float l0 = 0.0f, l1 = 0.0f;

    const unsigned short* gK = Kf + (size_t)(b * 2048) * 1024 + h * 64;
    const unsigned short* gV = VT + (size_t)(bh * 64) * 2048;
    const float* mrow = maskl + b * 2048;

    // hoisted, loop-invariant LDS read bases (imm offsets inside the loop)
    const unsigned short* kb4[4];
    const unsigned short* vb4[4];
#pragma unroll
    for (int ks = 0; ks < 4; ++ks) {
        const int cs = (2 * ks + hi) ^ sw;
        kb4[ks] = Ksh + q32 * 64 + cs * 8;
        vb4[ks] = Vsh + q32 * 128 + cs * 8;
    }

    // staging lane maps
    const int krr = lane >> 3;                 // K: row-in-group (8 rows/GLP)
    const int kcs = lane & 7;                  // K: slot
    const int vrr = lane >> 4;                 // V: row-in-group (4 rows/GLP)
    const int vcs = lane & 15;                 // V: slot (16/row)

    // stage K/V tile (kbn) into buffer at ushort offset so
    auto STAGE = [&](int kbn, int so) {
#pragma unroll
        for (int s = 0; s < 4; ++s) {
            const int seg = wv * 4 + s;                       // 0..15
            const int rK  = seg * 8 + krr;                    // key row 0..127
            const int cK  = kcs ^ (rK & 7);
            GLP(gK + (size_t)(kbn + rK) * 1024 + cK * 8, Ksh + so + seg * 512);
            const int rV  = seg * 4 + vrr;                    // d row 0..63
            const int cV  = vcs ^ (rV & 7);
            GLP(gV + (size_t)rV * 2048 + kbn + cV * 8, Vsh + so + seg * 512);
        }
    };

    // S-phase input read: K frags + mask C-operand for subtile t4 in buffer ro
    auto SREAD = [&](int t4, int ro, const float* mloc, short8 aK[4], floatx16& mC) {
        const int half = t4 >> 1, mt = t4 & 1;
#pragma unroll
        for (int ks = 0; ks < 4; ++ks)
            aK[ks] = *(const short8*)(kb4[ks] + ro + half * 4096 + mt * 2048);
        const float* mh = mloc + half * 64 + mt * 32;
#pragma unroll
        for (int a = 0; a < 4; ++a) {
            float4 mv = *(const float4*)(mh + a * 8);
            mC[4 * a + 0] = mv.x; mC[4 * a + 1] = mv.y;
            mC[4 * a + 2] = mv.z; mC[4 * a + 3] = mv.w;
        }
    };

    auto SMFMA = [&](const short8 aK[4], const floatx16& mC,
                     floatx16& s0, floatx16& s1) {
        __builtin_amdgcn_s_setprio(1);
        s0 = __builtin_amdgcn_mfma_f32_32x32x16_bf16(aK[0], bQ0[0], mC, 0, 0, 0);
        s1 = __builtin_amdgcn_mfma_f32_32x32x16_bf16(aK[0], bQ1[0], mC, 0, 0, 0);
#pragma unroll
        for (int ks = 1; ks < 4; ++ks) {
            s0 = __builtin_amdgcn_mfma_f32_32x32x16_bf16(aK[ks], bQ0[ks], s0, 0, 0, 0);
            s1 = __builtin_amdgcn_mfma_f32_32x32x16_bf16(aK[ks], bQ1[ks], s1, 0, 0, 0);
        }
        __builtin_amdgcn_s_setprio(0);
    };

    // One pipeline phase: exp/pack+PV of subtile `cur` (state sc*), and -- if
    // readNext -- ds_reads + S-MFMAs of subtile cur+1 into sn* (independent
    // chains; scheduler interleaves VALU exp with MFMA issue).
    auto PHASE = [&](int cur, int ro, const float* mloc, bool readNext,
                     floatx16& sc0, floatx16& sc1, floatx16& sn0, floatx16& sn1) {
        const int half = cur >> 1, mt = cur & 1;
        short8 aKn[4]; floatx16 mCn;
        if (readNext) SREAD(cur + 1, ro, mloc, aKn, mCn);
        // exp/pack q-subtile0 of cur (hides the SREAD latency)
        union { unsigned uu[4]; short8 s; } aPa, aPb, aPc, aPd;
        EXPPACKL(aPa, sc0, 0, l0);
        EXPPACKL(aPb, sc0, 8, l0);
        // V frags for cur (issued here; latency covered by SMFMA + exp below)
        short8 bVa0 = *(const short8*)(vb4[2 * mt + 0] + ro + half * 64);
        short8 bVa1 = *(const short8*)(vb4[2 * mt + 0] + ro + 4096 + half * 64);
        short8 bVb0 = *(const short8*)(vb4[2 * mt + 1] + ro + half * 64);
        short8 bVb1 = *(const short8*)(vb4[2 * mt + 1] + ro + 4096 + half * 64);
        // S-MFMAs of next (MFMA pipe) -- independent of the exp chain
        if (readNext) SMFMA(aKn, mCn, sn0, sn1);
        // exp/pack q-subtile1 of cur (VALU, overlaps MFMA occupancy above)
        EXPPACKL(aPc, sc1, 0, l1);
        EXPPACKL(aPd, sc1, 8, l1);
        // PV of cur
        __builtin_amdgcn_s_setprio(1);
        accO00 = __builtin_amdgcn_mfma_f32_32x32x16_bf16(aPa.s, bVa0, accO00, 0, 0, 0);
        accO01 = __builtin_amdgcn_mfma_f32_32x32x16_bf16(aPa.s, bVa1, accO01, 0, 0, 0);
        accO00 = __builtin_amdgcn_mfma_f32_32x32x16_bf16(aPb.s, bVb0, accO00, 0, 0, 0);
        accO01 = __builtin_amdgcn_mfma_f32_32x32x16_bf16(aPb.s, bVb1, accO01, 0, 0, 0);
        accO10 = __builtin_amdgcn_mfma_f32_32x32x16_bf16(aPc.s, bVa0, accO10, 0, 0, 0);
        accO11 = __builtin_amdgcn_mfma_f32_32x32x16_bf16(aPc.s, bVa1, accO11, 0, 0, 0);
        accO10 = __builtin_amdgcn_mfma_f32_32x32x16_bf16(aPd.s, bVb0, accO10, 0, 0, 0);
        accO11 = __builtin_amdgcn_mfma_f32_32x32x16_bf16(aPd.s, bVb1, accO11, 0, 0, 0);
        __builtin_amdgcn_s_setprio(0);
    };

    // one KV tile: prefetch t+1, then a 2-deep subtile pipeline over 4 subtiles
    auto TILE = [&](int kb, int ro, int so) {
        if (kb + 128 < 2048) STAGE(kb + 128, so);
        const float* mloc = Mall + kb + hi * 4;
        floatx16 sA0, sA1, sB0, sB1;
        {   // prime subtile 0
            short8 aK[4]; floatx16 mC;
            SREAD(0, ro, mloc, aK, mC);
            SMFMA(aK, mC, sA0, sA1);
        }
        __builtin_amdgcn_sched_barrier(0);
        PHASE(0, ro, mloc, true,  sA0, sA1, sB0, sB1);
        __builtin_amdgcn_sched_barrier(0);
        PHASE(1, ro, mloc, true,  sB0, sB1, sA0, sA1);
        __builtin_amdgcn_sched_barrier(0);
        PHASE(2, ro, mloc, true,  sA0, sA1, sB0, sB1);
        __builtin_amdgcn_sched_barrier(0);
        PHASE(3, ro, mloc, false, sB0, sB1, sA0, sA1);
        // prefetch (issued at tile top) has landed; drain is cheap. Barrier also
        // fences: everyone done reading buffer ro before next stage overwrites it.
        asm volatile("s_waitcnt vmcnt(0) lgkmcnt(0)" ::: "memory");
        __builtin_amdgcn_s_barrier();
    };

    // prologue: stage mask row (once) + tile 0 into buffer 0
#pragma unroll
    for (int s = 0; s < 2; ++s)
        GLP(mrow + (wv * 2 + s) * 256 + lane * 4, Mall + (wv * 2 + s) * 256);
    STAGE(0, 0);
    asm volatile("s_waitcnt vmcnt(0)" ::: "memory");
    __builtin_amdgcn_s_barrier();

#pragma unroll 1
    for (int kb2 = 0; kb2 < 2048; kb2 += 256) {
        TILE(kb2,       0,    8192);   // read buf0, stage -> buf1
        TILE(kb2 + 128, 8192, 0);      // read buf1, stage -> buf0
    }

    // l(q): combine the two hi-halves, redistribute to row-indexed layout via Lsh
    l0 += __shfl_xor(l0, 32, 64);
    l1 += __shfl_xor(l1, 32, 64);
    if (lane < 32) {
        Lsh[wv * 64 + q32]      = 1.0f / l0;
        Lsh[wv * 64 + 32 + q32] = 1.0f / l1;
    }
    // wave-synchronous: same wave wrote Lsh; compiler orders via lgkmcnt
#pragma unroll
    for (int g = 0; g < 4; ++g) {
        float4 i0 = *(const float4*)(Lsh + wv * 64 + g * 8 + hi * 4);
        float4 i1 = *(const float4*)(Lsh + wv * 64 + 32 + g * 8 + hi * 4);
#pragma unroll
        for (int rr = 0; rr < 4; ++rr) {
            const int r   = g * 4 + rr;
            const int row = rr + 8 * g + 4 * hi;
            const float l0v = (rr == 0) ? i0.x : (rr == 1) ? i0.y
                            : (rr == 2) ? i0.z : i0.w;
            const float l1v = (rr == 0) ? i1.x : (rr == 1) ? i1.y
                            : (rr == 2) ? i1.z : i1.w;
            float* op0 = out + (size_t)(b * 2048 + q0 + row) * 1024 + h * 64 + q32;
            float* op1 = out + (size_t)(b * 2048 + q0 + 32 + row) * 1024 + h * 64 + q32;
            op0[0]  = accO00[r] * l0v;
            op0[32] = accO01[r] * l0v;
            op1[0]  = accO10[r] * l1v;
            op1[32] = accO11[r] * l1v;
        }
    }
}

// ---------------- launch ----------------
extern "C" void kernel_launch(void* const* d_in, const int* in_sizes, int n_in,
                              void* d_out, int out_size, void* d_ws, size_t ws_size,
                              hipStream_t stream) {
    const float* X    = (const float*)d_in[0];
    const float* mask = (const float*)d_in[1];
    const float* Wq   = (const float*)d_in[2];
    const float* bq   = (const float*)d_in[3];
    const float* Wk   = (const float*)d_in[4];
    const float* bk   = (const float*)d_in[5];
    const float* Wv   = (const float*)d_in[6];
    const float* bv   = (const float*)d_in[7];
    float* out = (float*)d_out;

    char* ws = (char*)d_ws;
    unsigned short* xb  = (unsigned short*)(ws);                // 8192*1024 bf16 (16MB)
    unsigned short* wb  = (unsigned short*)(ws + 16777216);     // 3072*1024 bf16 (6MB)
    unsigned short* qf  = (unsigned short*)(ws + 23068672);     // [8192][1024] (16MB)
    unsigned short* kf  = (unsigned short*)(ws + 39845888);     // [8192][1024] (16MB)
    unsigned short* vtb = (unsigned short*)(ws + 56623104);     // [64*64][2048] (16MB)
    float*          ml  = (float*)(ws + 73400320);              // [4][2048] (32KB)

    cvt_all<<<11272, 256, 0, stream>>>(X, Wq, Wk, Wv, mask, xb, wb, ml);

    qkv_gemm<<<dim3(32, 12), 512, 0, stream>>>(xb, wb, bq, bk, bv, qf, kf, vtb);

    attn_kernel<<<512, 256, 0, stream>>>(qf, kf, vtb, ml, out);
}

// Round 9
// 334.065 us; speedup vs baseline: 1.2185x; 1.2185x over previous
//
#include <hip/hip_runtime.h>
#include <hip/hip_bf16.h>
#include <stdint.h>

// Problem constants: B=4, S=2048, D=1024, H=16, Dh=64
#define LOG2E 1.44269504088896340736f
#define SCL   (0.125f * LOG2E)   // folded into Q at the gemm epilogue

typedef __attribute__((ext_vector_type(8)))  short short8;     // 8 bf16 (4 VGPRs)
typedef __attribute__((ext_vector_type(16))) float floatx16;   // 32x32 C/D frag
typedef __attribute__((ext_vector_type(4)))  unsigned short ushort4v;

// global -> LDS direct DMA, 16B/lane. LDS dest is HW-fixed: wave-uniform base + lane*16.
#define GLP(g, l)                                                              \
    __builtin_amdgcn_global_load_lds(                                          \
        (const __attribute__((address_space(1))) void*)(g),                    \
        (__attribute__((address_space(3))) void*)(l), 16, 0, 0)

#if __has_builtin(__builtin_amdgcn_exp2f)
#define EXP2(x) __builtin_amdgcn_exp2f(x)   // raw v_exp_f32 (args bounded here)
#else
#define EXP2(x) exp2f(x)
#endif

static __device__ __forceinline__ unsigned short f2bf(float f) {
    union { float f; unsigned u; } v; v.f = f;
    unsigned r = v.u + 0x7FFFu + ((v.u >> 16) & 1u);  // RNE
    return (unsigned short)(r >> 16);
}

static __device__ __forceinline__ unsigned pack2bf(float a, float b) {
    __hip_bfloat162 h = __float22bfloat162_rn(make_float2(a, b));
    union { __hip_bfloat162 h; unsigned u; } c; c.h = h; return c.u;
}

// exp2 8 consecutive S-regs -> one bf16x8 PV A-frag + running l accumulation
#define EXPPACKL(dst, sv, base, lacc) do {                                     \
        float p0 = EXP2((sv)[(base) + 0]), p1 = EXP2((sv)[(base) + 1]);        \
        float p2 = EXP2((sv)[(base) + 2]), p3 = EXP2((sv)[(base) + 3]);        \
        float p4 = EXP2((sv)[(base) + 4]), p5 = EXP2((sv)[(base) + 5]);        \
        float p6 = EXP2((sv)[(base) + 6]), p7 = EXP2((sv)[(base) + 7]);        \
        lacc += ((p0 + p1) + (p2 + p3)) + ((p4 + p5) + (p6 + p7));             \
        dst.uu[0] = pack2bf(p0, p1); dst.uu[1] = pack2bf(p2, p3);              \
        dst.uu[2] = pack2bf(p4, p5); dst.uu[3] = pack2bf(p6, p7);              \
    } while (0)

// ------- merged fp32->bf16 convert: X | Wq|Wk|Wv | mask(xLOG2E) in one launch -------
__global__ __launch_bounds__(256) void cvt_all(const float* __restrict__ X,
                                               const float* __restrict__ Wq,
                                               const float* __restrict__ Wk,
                                               const float* __restrict__ Wv,
                                               const float* __restrict__ mask,
                                               unsigned short* __restrict__ xb,
                                               unsigned short* __restrict__ wb,
                                               float* __restrict__ maskl) {
    int i = blockIdx.x * 256 + threadIdx.x;   // 2097152 X + 786432 W + 2048 mask float4s
    if (i < 2097152) {
        float4 v = ((const float4*)X)[i];
        ushort4v o;
        o.x = f2bf(v.x); o.y = f2bf(v.y); o.z = f2bf(v.z); o.w = f2bf(v.w);
        ((ushort4v*)xb)[i] = o;
    } else if (i < 2883584) {
        int j = i - 2097152;
        const float* src; int k;
        if (j < 262144)      { src = Wq; k = j; }
        else if (j < 524288) { src = Wk; k = j - 262144; }
        else                 { src = Wv; k = j - 524288; }
        float4 v = ((const float4*)src)[k];
        ushort4v o;
        o.x = f2bf(v.x); o.y = f2bf(v.y); o.z = f2bf(v.z); o.w = f2bf(v.w);
        ((ushort4v*)wb)[j] = o;
    } else if (i < 2883584 + 2048) {
        int j = i - 2883584;
        float4 v = ((const float4*)mask)[j];
        ((float4*)maskl)[j] = make_float4(v.x * LOG2E, v.y * LOG2E,
                                          v.z * LOG2E, v.w * LOG2E);
    }
}

// ---------------- fused QKV projection GEMM (32x32x16 MFMA) ----------------
// (R7 structure, kept: 256x256 block, 8 waves as 2Mx4N -> 128x64 wave-tiles,
// dbuf 128KB LDS, prefetch-first + one vmcnt(0)+barrier per BK=64 tile.)
__global__ __launch_bounds__(512)
__attribute__((amdgpu_waves_per_eu(2, 2))) void qkv_gemm(
        const unsigned short* __restrict__ X,   // [8192][1024] bf16
        const unsigned short* __restrict__ W,   // [3072][1024] bf16
        const float* __restrict__ bq, const float* __restrict__ bk,
        const float* __restrict__ bv,
        unsigned short* __restrict__ Qf,        // [8192][1024]  (pre-scaled by SCL)
        unsigned short* __restrict__ Kf,        // [8192][1024]
        unsigned short* __restrict__ Vt)        // [64*64][2048], key-permuted
{
    // A slot0 @0, A slot1 @16384, B slot0 @32768, B slot1 @49152 (ushorts)
    __shared__ __align__(16) unsigned short AB[65536];          // 128 KB

    const int tid  = threadIdx.x;
    const int lane = tid & 63;
    const int wv   = tid >> 6;            // 0..7
    const int q32  = lane & 31;
    const int hi   = lane >> 5;
    const int sw   = q32 & 7;
    const int mBase = blockIdx.x * 256;
    const int nBase = blockIdx.y * 256;
    const int wm = (wv >> 2) * 128;       // 0 or 128
    const int wn = (wv & 3) * 64;         // 0,64,128,192

    floatx16 acc[4][2];
#pragma unroll
    for (int mi = 0; mi < 4; ++mi) { acc[mi][0] = 0.0f; acc[mi][1] = 0.0f; }

    const int sr = lane >> 3;             // 0..7 row-in-group
    const int kc = (lane & 7) ^ sr;       // swizzled 16B chunk

    // hoisted LDS read bases (R&7 == sw since wm, mi*32, wn, ni*32 are mult of 8)
    const unsigned short* aBase[4];
    const unsigned short* bBase[4];
#pragma unroll
    for (int ks = 0; ks < 4; ++ks) {
        const int cs = ((2 * ks + hi) ^ sw) * 8;
        aBase[ks] = AB + ((wv >> 2) * 16 + (q32 >> 3)) * 512 + sw * 64 + cs;
        bBase[ks] = AB + 32768 + ((wv & 3) * 8 + (q32 >> 3)) * 512 + sw * 64 + cs;
    }

    // stage K-tile (kb) into slot (ushort offset so): 4 rounds x (1 A + 1 B) GLP
    auto STAGE = [&](int kb, int so) {
#pragma unroll
        for (int r = 0; r < 4; ++r) {
            const int seg = r * 8 + wv;                      // 0..31
            const int row = seg * 8 + sr;                    // 0..255
            GLP(X + (size_t)(mBase + row) * 1024 + kb + kc * 8, AB + so + seg * 512);
            GLP(W + (size_t)(nBase + row) * 1024 + kb + kc * 8, AB + 32768 + so + seg * 512);
        }
    };

    // prologue: stage tile 0 -> slot 0
    STAGE(0, 0);
    asm volatile("s_waitcnt vmcnt(0)" ::: "memory");
    __builtin_amdgcn_s_barrier();

#pragma unroll 1
    for (int t = 0; t < 16; ++t) {
        const int so  = (t & 1) * 16384;
        // prefetch tile t+1 into the slot freed at the end of tile t-1
        if (t < 15) STAGE((t + 1) * 64, ((t + 1) & 1) * 16384);
        // compute tile t
        short8 bF[2][4];
#pragma unroll
        for (int ni = 0; ni < 2; ++ni)
#pragma unroll
            for (int ks = 0; ks < 4; ++ks)
                bF[ni][ks] = *(const short8*)(bBase[ks] + so + ni * 2048);
#pragma unroll
        for (int mi = 0; mi < 4; ++mi) {
            short8 aF[4];
#pragma unroll
            for (int ks = 0; ks < 4; ++ks)
                aF[ks] = *(const short8*)(aBase[ks] + so + mi * 2048);
#pragma unroll
            for (int ks = 0; ks < 4; ++ks) {
                acc[mi][0] = __builtin_amdgcn_mfma_f32_32x32x16_bf16(
                    aF[ks], bF[0][ks], acc[mi][0], 0, 0, 0);
                acc[mi][1] = __builtin_amdgcn_mfma_f32_32x32x16_bf16(
                    aF[ks], bF[1][ks], acc[mi][1], 0, 0, 0);
            }
        }
        // own ds_reads drained (lgkm) + prefetch landed (vm); barrier frees slot so
        asm volatile("s_waitcnt vmcnt(0) lgkmcnt(0)" ::: "memory");
        __builtin_amdgcn_s_barrier();
    }

    // 32x32 C/D layout: col = lane&31, row = (r&3) + 8*(r>>2) + 4*hi (+ mi*32)
    if (blockIdx.y < 8) {
        // ---- Q or K: LDS transpose (two 128-row halves) -> coalesced stores ----
        unsigned short* dst = (blockIdx.y < 4) ? Qf : Kf;
        const float* bias   = (blockIdx.y < 4) ? bq : bk;
        const float scl     = (blockIdx.y < 4) ? SCL : 1.0f;
        const int nb = nBase & 1023;
        float bj[2];
#pragma unroll
        for (int ni = 0; ni < 2; ++ni)
            bj[ni] = bias[nb + wn + ni * 32 + q32];
#pragma unroll 1
        for (int hh = 0; hh < 2; ++hh) {
            if ((wm >> 7) == hh) {   // the 4 waves owning this M-half stage it
#pragma unroll
                for (int ni = 0; ni < 2; ++ni) {
                    const int col = wn + ni * 32 + q32;
#pragma unroll
                    for (int mi = 0; mi < 4; ++mi)
#pragma unroll
                        for (int g = 0; g < 4; ++g) {
                            const int row0 = mi * 32 + g * 8 + hi * 4;
#pragma unroll
                            for (int rr = 0; rr < 4; ++rr)
                                AB[(row0 + rr) * 264 + col] =
                                    f2bf((acc[mi][ni][g * 4 + rr] + bj[ni]) * scl);
                        }
                }
            }
            __syncthreads();
            // 128 rows x 32 parts; 512 threads -> 16 rows/iter, 8 iters
#pragma unroll
            for (int it = 0; it < 8; ++it) {
                const int row  = it * 16 + (tid >> 5);
                const int part = tid & 31;
                short8 v = *(const short8*)(AB + row * 264 + part * 8);
                *(short8*)(dst + (size_t)(mBase + hh * 128 + row) * 1024
                               + nb + part * 8) = v;
            }
            __syncthreads();   // before the other half overwrites AB
        }
    } else {
        // ---- V: transposed stores with key bits 2<->3 swapped (quad-aligned) ----
#pragma unroll
        for (int ni = 0; ni < 2; ++ni) {
            const int c = (nBase - 2048) + wn + ni * 32 + q32;   // 0..1023
            const int h = c >> 6;
            const int d = c & 63;
            const float bias = bv[c];
#pragma unroll
            for (int mi = 0; mi < 4; ++mi)
#pragma unroll
                for (int g = 0; g < 4; ++g) {
                    const int m0 = mBase + wm + mi * 32 + g * 8 + hi * 4;
                    const int b  = m0 >> 11;
                    const int s0 = m0 & 2047;
                    const int sp = (s0 & ~12) | ((s0 & 4) << 1) | ((s0 & 8) >> 1);
                    ushort4v pv;
#pragma unroll
                    for (int rr = 0; rr < 4; ++rr)
                        pv[rr] = f2bf(acc[mi][ni][g * 4 + rr] + bias);
                    *(ushort4v*)(Vt + (size_t)((b * 16 + h) * 64 + d) * 2048 + sp) = pv;
                }
        }
    }
}

// ---------------- flash attention: 32x32 MFMA, S^T, zero-exchange P ----------------
// R9: DEFERRED-PV pipeline, single P-set. R8's corrected pipe model: one
// 32x32x16 MFMA occupies its SIMD ~32 cyc (the 8.07 figure is per-CU/4 SIMDs);
// R6's pipes were MFMA 34.5 + TRANS/VALU 39 + LDS 23 ~= 91us SERIALIZED.
// A wave issues in order, so in [SMFMA -> exp -> PV] the exp stall leaves the
// MFMA pipe empty. Fix with NO extra S-state (R3/R8 spilled on a 2nd S-state):
// per subtile t: [SREAD(t)][SMFMA(t)][sched_barrier][PV(t-1) -- data-ready,
// issues while exp(t) waits on s(t)][EXP(t) -> P][BVREAD(t)]. Only one P-set
// (aP 16 + bV 16) is ever live: P(t-1) dies in PV before P(t) is built.
// Ones-trick dropped (-4 MFMA/subtile, -32 held regs); l on VALU adds
// (overlapped with PV) + R4-verified Lsh epilogue. Peak live ~230 < 256.
__global__ __launch_bounds__(256)
__attribute__((amdgpu_waves_per_eu(2, 2))) void attn_kernel(
        const unsigned short* __restrict__ Qf,   // [8192][1024] bf16 (x SCL)
        const unsigned short* __restrict__ Kf,   // [8192][1024] bf16
        const unsigned short* __restrict__ VT,   // [64*64][2048] bf16, key-permuted
        const float* __restrict__ maskl,         // [4][2048], pre-scaled by LOG2E
        float* __restrict__ out)                 // [4][2048][1024]
{
    __shared__ __align__(16) unsigned short Ksh[2 * 128 * 64]; // 2 x (128 keys x 64 d)
    __shared__ __align__(16) unsigned short Vsh[2 * 64 * 128]; // 2 x (64 d x 128 keys)
    __shared__ __align__(16) float Mall[2048];                 // whole mask row, once
    __shared__ __align__(16) float Lsh[256];                   // 1/l(q), end only

    const int tid  = threadIdx.x;
    const int lane = tid & 63;
    const int wv   = tid >> 6;
    const int q32  = lane & 31;
    const int hi   = lane >> 5;
    const int bh   = blockIdx.x & 63;
    const int qt   = blockIdx.x >> 6;                // 0..7
    const int b    = bh >> 4;
    const int h    = bh & 15;
    const int q0   = qt * 256 + wv * 64;             // wave owns 64 queries
    const int sw   = q32 & 7;                        // per-lane XOR swizzle key

    // Q as B-operand fragments for both q-subtiles, hoisted out of K-loop
    short8 bQ0[4], bQ1[4];
#pragma unroll
    for (int ks = 0; ks < 4; ++ks) {
        bQ0[ks] = *(const short8*)(Qf + (size_t)(b * 2048 + q0 + q32) * 1024
                                      + h * 64 + ks * 16 + hi * 8);
        bQ1[ks] = *(const short8*)(Qf + (size_t)(b * 2048 + q0 + 32 + q32) * 1024
                                      + h * 64 + ks * 16 + hi * 8);
    }

    floatx16 accO00 = 0.0f, accO01 = 0.0f;   // qsub0: d-lo, d-hi
    floatx16 accO10 = 0.0f, accO11 = 0.0f;   // qsub1
    float l0 = 0.0f, l1 = 0.0f;

    const unsigned short* gK = Kf + (size_t)(b * 2048) * 1024 + h * 64;
    const unsigned short* gV = VT + (size_t)(bh * 64) * 2048;
    const float* mrow = maskl + b * 2048;

    // hoisted, loop-invariant LDS read bases (imm offsets inside the loop)
    const unsigned short* kb4[4];
    const unsigned short* vb4[4];
#pragma unroll
    for (int ks = 0; ks < 4; ++ks) {
        const int cs = (2 * ks + hi) ^ sw;
        kb4[ks] = Ksh + q32 * 64 + cs * 8;
        vb4[ks] = Vsh + q32 * 128 + cs * 8;
    }

    // staging lane maps
    const int krr = lane >> 3;                 // K: row-in-group (8 rows/GLP)
    const int kcs = lane & 7;                  // K: slot
    const int vrr = lane >> 4;                 // V: row-in-group (4 rows/GLP)
    const int vcs = lane & 15;                 // V: slot (16/row)

    // stage K/V tile (kbn) into buffer at ushort offset so
    auto STAGE = [&](int kbn, int so) {
#pragma unroll
        for (int s = 0; s < 4; ++s) {
            const int seg = wv * 4 + s;                       // 0..15
            const int rK  = seg * 8 + krr;                    // key row 0..127
            const int cK  = kcs ^ (rK & 7);
            GLP(gK + (size_t)(kbn + rK) * 1024 + cK * 8, Ksh + so + seg * 512);
            const int rV  = seg * 4 + vrr;                    // d row 0..63
            const int cV  = vcs ^ (rV & 7);
            GLP(gV + (size_t)rV * 2048 + kbn + cV * 8, Vsh + so + seg * 512);
        }
    };

    union P4 { unsigned uu[4]; short8 s; };

    // one KV tile: prefetch t+1, then deferred-PV pipeline over 4 subtiles
    auto TILE = [&](int kb, int ro, int so) {
        if (kb + 128 < 2048) STAGE(kb + 128, so);
        const float* mloc = Mall + kb + hi * 4;
        P4 aPa, aPb, aPc, aPd;                 // single P-set (rebuilt per subtile)
        short8 bVa0, bVa1, bVb0, bVb1;
#pragma unroll
        for (int t4 = 0; t4 < 4; ++t4) {
            const int half = t4 >> 1, mt = t4 & 1;
            // --- SREAD(t): K frags + mask C-operand ---
            short8 aK[4];
#pragma unroll
            for (int ks = 0; ks < 4; ++ks)
                aK[ks] = *(const short8*)(kb4[ks] + ro + half * 4096 + mt * 2048);
            floatx16 mC;
#pragma unroll
            for (int a = 0; a < 4; ++a) {
                float4 mv = *(const float4*)(mloc + half * 64 + mt * 32 + a * 8);
                mC[4 * a + 0] = mv.x; mC[4 * a + 1] = mv.y;
                mC[4 * a + 2] = mv.z; mC[4 * a + 3] = mv.w;
            }
            // --- SMFMA(t) ---
            __builtin_amdgcn_s_setprio(1);
            floatx16 s0 = __builtin_amdgcn_mfma_f32_32x32x16_bf16(aK[0], bQ0[0], mC, 0, 0, 0);
            floatx16 s1 = __builtin_amdgcn_mfma_f32_32x32x16_bf16(aK[0], bQ1[0], mC, 0, 0, 0);
#pragma unroll
            for (int ks = 1; ks < 4; ++ks) {
                s0 = __builtin_amdgcn_mfma_f32_32x32x16_bf16(aK[ks], bQ0[ks], s0, 0, 0, 0);
                s1 = __builtin_amdgcn_mfma_f32_32x32x16_bf16(aK[ks], bQ1[ks], s1, 0, 0, 0);
            }
            __builtin_amdgcn_s_setprio(0);
            // pin: PV(t-1) stays below SMFMA(t) so it fills the exp-wait gap,
            // not the (smaller) lgkm wait above.
            __builtin_amdgcn_sched_barrier(0);
            // --- PV(t-1): data-ready MFMAs issue while exp(t) waits on s(t) ---
            if (t4 > 0) {
                __builtin_amdgcn_s_setprio(1);
                accO00 = __builtin_amdgcn_mfma_f32_32x32x16_bf16(aPa.s, bVa0, accO00, 0, 0, 0);
                accO01 = __builtin_amdgcn_mfma_f32_32x32x16_bf16(aPa.s, bVa1, accO01, 0, 0, 0);
                accO00 = __builtin_amdgcn_mfma_f32_32x32x16_bf16(aPb.s, bVb0, accO00, 0, 0, 0);
                accO01 = __builtin_amdgcn_mfma_f32_32x32x16_bf16(aPb.s, bVb1, accO01, 0, 0, 0);
                accO10 = __builtin_amdgcn_mfma_f32_32x32x16_bf16(aPc.s, bVa0, accO10, 0, 0, 0);
                accO11 = __builtin_amdgcn_mfma_f32_32x32x16_bf16(aPc.s, bVa1, accO11, 0, 0, 0);
                accO10 = __builtin_amdgcn_mfma_f32_32x32x16_bf16(aPd.s, bVb0, accO10, 0, 0, 0);
                accO11 = __builtin_amdgcn_mfma_f32_32x32x16_bf16(aPd.s, bVb1, accO11, 0, 0, 0);
                __builtin_amdgcn_s_setprio(0);
            }
            // --- EXP(t): overlaps PV(t-1) pipe occupancy ---
            EXPPACKL(aPa, s0, 0, l0);
            EXPPACKL(aPb, s0, 8, l0);
            EXPPACKL(aPc, s1, 0, l1);
            EXPPACKL(aPd, s1, 8, l1);
            // --- BVREAD(t): V frags for this subtile's PV (next phase) ---
            bVa0 = *(const short8*)(vb4[2 * mt + 0] + ro + half * 64);
            bVa1 = *(const short8*)(vb4[2 * mt + 0] + ro + 4096 + half * 64);
            bVb0 = *(const short8*)(vb4[2 * mt + 1] + ro + half * 64);
            bVb1 = *(const short8*)(vb4[2 * mt + 1] + ro + 4096 + half * 64);
        }
        // --- tail: PV(3) ---
        __builtin_amdgcn_s_setprio(1);
        accO00 = __builtin_amdgcn_mfma_f32_32x32x16_bf16(aPa.s, bVa0, accO00, 0, 0, 0);
        accO01 = __builtin_amdgcn_mfma_f32_32x32x16_bf16(aPa.s, bVa1, accO01, 0, 0, 0);
        accO00 = __builtin_amdgcn_mfma_f32_32x32x16_bf16(aPb.s, bVb0, accO00, 0, 0, 0);
        accO01 = __builtin_amdgcn_mfma_f32_32x32x16_bf16(aPb.s, bVb1, accO01, 0, 0, 0);
        accO10 = __builtin_amdgcn_mfma_f32_32x32x16_bf16(aPc.s, bVa0, accO10, 0, 0, 0);
        accO11 = __builtin_amdgcn_mfma_f32_32x32x16_bf16(aPc.s, bVa1, accO11, 0, 0, 0);
        accO10 = __builtin_amdgcn_mfma_f32_32x32x16_bf16(aPd.s, bVb0, accO10, 0, 0, 0);
        accO11 = __builtin_amdgcn_mfma_f32_32x32x16_bf16(aPd.s, bVb1, accO11, 0, 0, 0);
        __builtin_amdgcn_s_setprio(0);
        // prefetch (issued at tile top) has landed; drain is cheap. Barrier also
        // fences: everyone done reading buffer ro before next stage overwrites it.
        asm volatile("s_waitcnt vmcnt(0) lgkmcnt(0)" ::: "memory");
        __builtin_amdgcn_s_barrier();
    };

    // prologue: stage mask row (once) + tile 0 into buffer 0
#pragma unroll
    for (int s = 0; s < 2; ++s)
        GLP(mrow + (wv * 2 + s) * 256 + lane * 4, Mall + (wv * 2 + s) * 256);
    STAGE(0, 0);
    asm volatile("s_waitcnt vmcnt(0)" ::: "memory");
    __builtin_amdgcn_s_barrier();

#pragma unroll 1
    for (int kb2 = 0; kb2 < 2048; kb2 += 256) {
        TILE(kb2,       0,    8192);   // read buf0, stage -> buf1
        TILE(kb2 + 128, 8192, 0);      // read buf1, stage -> buf0
    }

    // l(q): combine the two hi-halves, redistribute to row-indexed layout via Lsh
    l0 += __shfl_xor(l0, 32, 64);
    l1 += __shfl_xor(l1, 32, 64);
    if (lane < 32) {
        Lsh[wv * 64 + q32]      = 1.0f / l0;
        Lsh[wv * 64 + 32 + q32] = 1.0f / l1;
    }
    // wave-synchronous: same wave wrote Lsh; compiler orders via lgkmcnt
#pragma unroll
    for (int g = 0; g < 4; ++g) {
        float4 i0 = *(const float4*)(Lsh + wv * 64 + g * 8 + hi * 4);
        float4 i1 = *(const float4*)(Lsh + wv * 64 + 32 + g * 8 + hi * 4);
#pragma unroll
        for (int rr = 0; rr < 4; ++rr) {
            const int r   = g * 4 + rr;
            const int row = rr + 8 * g + 4 * hi;
            const float l0v = (rr == 0) ? i0.x : (rr == 1) ? i0.y
                            : (rr == 2) ? i0.z : i0.w;
            const float l1v = (rr == 0) ? i1.x : (rr == 1) ? i1.y
                            : (rr == 2) ? i1.z : i1.w;
            float* op0 = out + (size_t)(b * 2048 + q0 + row) * 1024 + h * 64 + q32;
            float* op1 = out + (size_t)(b * 2048 + q0 + 32 + row) * 1024 + h * 64 + q32;
            op0[0]  = accO00[r] * l0v;
            op0[32] = accO01[r] * l0v;
            op1[0]  = accO10[r] * l1v;
            op1[32] = accO11[r] * l1v;
        }
    }
}

// ---------------- launch ----------------
extern "C" void kernel_launch(void* const* d_in, const int* in_sizes, int n_in,
                              void* d_out, int out_size, void* d_ws, size_t ws_size,
                              hipStream_t stream) {
    const float* X    = (const float*)d_in[0];
    const float* mask = (const float*)d_in[1];
    const float* Wq   = (const float*)d_in[2];
    const float* bq   = (const float*)d_in[3];
    const float* Wk   = (const float*)d_in[4];
    const float* bk   = (const float*)d_in[5];
    const float* Wv   = (const float*)d_in[6];
    const float* bv   = (const float*)d_in[7];
    float* out = (float*)d_out;

    char* ws = (char*)d_ws;
    unsigned short* xb  = (unsigned short*)(ws);                // 8192*1024 bf16 (16MB)
    unsigned short* wb  = (unsigned short*)(ws + 16777216);     // 3072*1024 bf16 (6MB)
    unsigned short* qf  = (unsigned short*)(ws + 23068672);     // [8192][1024] (16MB)
    unsigned short* kf  = (unsigned short*)(ws + 39845888);     // [8192][1024] (16MB)
    unsigned short* vtb = (unsigned short*)(ws + 56623104);     // [64*64][2048] (16MB)
    float*          ml  = (float*)(ws + 73400320);              // [4][2048] (32KB)

    cvt_all<<<11272, 256, 0, stream>>>(X, Wq, Wk, Wv, mask, xb, wb, ml);

    qkv_gemm<<<dim3(32, 12), 512, 0, stream>>>(xb, wb, bq, bk, bv, qf, kf, vtb);

    attn_kernel<<<512, 256, 0, stream>>>(qf, kf, vtb, ml, out);
}